// Round 2
// baseline (1555.847 us; speedup 1.0000x reference)
//
#include <hip/hip_runtime.h>
#include <hip/hip_bf16.h>

#define BATCH  32
#define SEQ    1024
#define DMODEL 384
#define DINNER 768
#define DSTATE 16
#define DTRANK 24
#define NTOK   (BATCH * SEQ)
#define TC     32             // time chunks for parallel scan
#define CL     (SEQ / TC)     // 32 steps per chunk
#define DTR_R  16             // tokens per dt block

typedef __hip_bfloat16 bf16;
typedef __attribute__((ext_vector_type(8))) short frag_ab;  // 8 bf16
typedef __attribute__((ext_vector_type(4))) float frag_cd;  // 4 f32

__device__ __forceinline__ float b2f(bf16 v) { return __bfloat162float(v); }
__device__ __forceinline__ bf16  f2b(float v) { return __float2bfloat16(v); }
__device__ __forceinline__ float ldx(const void* p, size_t i, bool f32m) {
    return f32m ? ((const float*)p)[i] : b2f(((const bf16*)p)[i]);
}

// ------------------------------------------------------------------
// Input-dtype detection (f32 vs bf16). Verified R5: inputs are f32.
// ------------------------------------------------------------------
__global__ void detect_kernel(const unsigned short* __restrict__ x, int* flag) {
    int bad = 0;
    for (int i = threadIdx.x; i < 16384; i += 256) {
        int e = (x[i] >> 7) & 0xFF;
        bad |= (e >= 0xE0);
    }
    if (bad) atomicOr(flag, 1);
}

// ------------------------------------------------------------------
// A-structure check: Av[n]/Av[0] == n+1 (A_log = log(1..16) broadcast).
// Sets flag[1]=1 if NOT structured -> scan uses generic 16-exp path.
// ------------------------------------------------------------------
__global__ void struct_check(const float* __restrict__ alog, int* flag) {
    int c = blockIdx.x * 256 + threadIdx.x;
    if (c >= DINNER) return;
    float a0 = __expf(alog[c * 16]);
    int bad = 0;
#pragma unroll
    for (int n = 1; n < DSTATE; ++n) {
        float r = __expf(alog[c * 16 + n]) / a0;
        bad |= (fabsf(r - (float)(n + 1)) > 1e-3f * (n + 1));
    }
    if (bad) atomicOr(flag + 1, 1);
}

// ------------------------------------------------------------------
// Weight conversion: small params -> f32, GEMM weights -> bf16.
// ------------------------------------------------------------------
struct CvtF { const void* src[15]; float* dst[15]; int n[15]; };
struct CvtB { const void* src[7];  bf16*  dst[7];  int n[7];  };

__global__ void convert_f_kernel(CvtF p, const int* __restrict__ flag) {
    bool f32m = (*flag != 0);
    int y = blockIdx.y;
    const void* s = p.src[y];
    float* d = p.dst[y];
    int n = p.n[y];
    for (int i = blockIdx.x * 256 + threadIdx.x; i < n; i += gridDim.x * 256)
        d[i] = ldx(s, i, f32m);
}
__global__ void convert_b_kernel(CvtB p, const int* __restrict__ flag) {
    bool f32m = (*flag != 0);
    int y = blockIdx.y;
    const void* s = p.src[y];
    bf16* d = p.dst[y];
    int n = p.n[y];
    for (int i = blockIdx.x * 256 + threadIdx.x; i < n; i += gridDim.x * 256)
        d[i] = f2b(ldx(s, i, f32m));
}

// ------------------------------------------------------------------
// dtw transpose: [768][24] f32 -> [24][768] f32 so dt_kernel loads are
// coalesced (consecutive channels = consecutive addresses).
// ------------------------------------------------------------------
__global__ void transpose_dtw(const float* __restrict__ w, float* __restrict__ wt) {
    int i = blockIdx.x * 256 + threadIdx.x;
    if (i >= DINNER * DTRANK) return;
    int c = i / DTRANK, r = i % DTRANK;
    wt[r * DINNER + c] = w[i];
}

// ------------------------------------------------------------------
// LayerNorm: one wave per row of 384; writes bf16 xn.
// ------------------------------------------------------------------
__global__ void ln_kernel(const void* __restrict__ x, size_t xoff,
                          const float* __restrict__ gamma, const float* __restrict__ beta,
                          bf16* __restrict__ xn, const int* __restrict__ flag) {
    bool f32m = (*flag != 0);
    int wave = threadIdx.x >> 6;
    int lane = threadIdx.x & 63;
    int row  = blockIdx.x * 4 + wave;
    size_t base = xoff + (size_t)row * DMODEL;
    float v[6];
    float s = 0.f, s2 = 0.f;
#pragma unroll
    for (int i = 0; i < 6; ++i) {
        v[i] = ldx(x, base + lane + i * 64, f32m);
        s += v[i];
        s2 += v[i] * v[i];
    }
#pragma unroll
    for (int off = 32; off >= 1; off >>= 1) {
        s  += __shfl_down(s, off, 64);
        s2 += __shfl_down(s2, off, 64);
    }
    s  = __shfl(s, 0, 64);
    s2 = __shfl(s2, 0, 64);
    float mu   = s / DMODEL;
    float var  = s2 / DMODEL - mu * mu;
    float rstd = rsqrtf(var + 1e-5f);
    bf16* xnr = xn + (size_t)row * DMODEL;
#pragma unroll
    for (int i = 0; i < 6; ++i)
        xnr[lane + i * 64] = f2b((v[i] - mu) * rstd * gamma[lane + i * 64] + beta[lane + i * 64]);
}

// ------------------------------------------------------------------
// MFMA bf16 GEMM, 128x128 tile, BK=32, 256 threads (2x2 waves of 64x64).
// C[M,N] = A[M,K] @ W[N,K]^T.
// MODE 0: bf16 store (ldc, cofs).        MODE 1: gate epilogue -> d_out.
// MODE 2: f32 store, 56 valid cols.      MODE 3: z epilogue: C *= silu(v).
// ------------------------------------------------------------------
template <int MODE>
__global__ __launch_bounds__(256) void gemm_mfma(
    const bf16* __restrict__ A, const bf16* __restrict__ W,
    int K, int lda, int ldw,
    bf16* __restrict__ C, int ldc, int cofs,
    float* __restrict__ Cf,
    const float* __restrict__ gb, const void* __restrict__ xg, size_t xoff,
    void* __restrict__ outg, const int* __restrict__ flag) {
    __shared__ bf16 Als[128][32];
    __shared__ bf16 Bls[128][32];
    int tid = threadIdx.x;
    int lane = tid & 63;
    int w = tid >> 6;
    int wm = w & 1, wn = w >> 1;
    int m0 = blockIdx.y * 128, n0 = blockIdx.x * 128;
    int row = tid >> 2, kc = tid & 3;
    int mr = lane & 15, quad = lane >> 4;

    frag_cd acc[4][4] = {};

    for (int k0 = 0; k0 < K; k0 += 32) {
        uint4 a0 = *(const uint4*)(A + (size_t)(m0 + row) * lda + k0 + kc * 8);
        uint4 a1 = *(const uint4*)(A + (size_t)(m0 + 64 + row) * lda + k0 + kc * 8);
        uint4 b0 = *(const uint4*)(W + (size_t)(n0 + row) * ldw + k0 + kc * 8);
        uint4 b1 = *(const uint4*)(W + (size_t)(n0 + 64 + row) * ldw + k0 + kc * 8);
        __syncthreads();
        *(uint4*)&Als[row][kc * 8]      = a0;
        *(uint4*)&Als[64 + row][kc * 8] = a1;
        *(uint4*)&Bls[row][kc * 8]      = b0;
        *(uint4*)&Bls[64 + row][kc * 8] = b1;
        __syncthreads();
        frag_ab af[4], bfr[4];
#pragma unroll
        for (int r = 0; r < 4; ++r)
            af[r] = *(const frag_ab*)&Als[wm * 64 + r * 16 + mr][quad * 8];
#pragma unroll
        for (int c = 0; c < 4; ++c)
            bfr[c] = *(const frag_ab*)&Bls[wn * 64 + c * 16 + mr][quad * 8];
#pragma unroll
        for (int r = 0; r < 4; ++r)
#pragma unroll
            for (int c = 0; c < 4; ++c)
                acc[r][c] = __builtin_amdgcn_mfma_f32_16x16x32_bf16(af[r], bfr[c], acc[r][c], 0, 0, 0);
    }

    bool f32m = (MODE == 1) ? (*flag != 0) : false;
#pragma unroll
    for (int r = 0; r < 4; ++r) {
#pragma unroll
        for (int c = 0; c < 4; ++c) {
#pragma unroll
            for (int reg = 0; reg < 4; ++reg) {
                int gm = m0 + wm * 64 + r * 16 + quad * 4 + reg;
                int gn = n0 + wn * 64 + c * 16 + mr;
                float v = acc[r][c][reg];
                if (MODE == 0) {
                    C[(size_t)gm * ldc + cofs + gn] = f2b(v);
                } else if (MODE == 2) {
                    if (gn < DTRANK + 2 * DSTATE) Cf[(size_t)gm * 56 + gn] = v;
                } else if (MODE == 3) {  // ydir *= silu(z),  v == z
                    size_t idx = (size_t)gm * ldc + cofs + gn;
                    float y = b2f(C[idx]);
                    float sz = v / (1.f + __expf(-v));
                    C[idx] = f2b(y * sz);
                } else {  // gate: g*yf + (1-g)*yb + x  (A == ycat)
                    float g   = 1.f / (1.f + __expf(-(v + gb[gn])));
                    float yfv = b2f(A[(size_t)gm * DINNER + gn]);
                    float ybv = b2f(A[(size_t)gm * DINNER + DMODEL + gn]);
                    size_t gi = xoff + (size_t)gm * DMODEL + gn;
                    float xv  = f32m ? ((const float*)xg)[gi] : b2f(((const bf16*)xg)[gi]);
                    float rr  = g * yfv + (1.f - g) * ybv + xv;
                    if (f32m) ((float*)outg)[gi] = rr;
                    else      ((bf16*)outg)[gi]  = f2b(rr);
                }
            }
        }
    }
}

// ------------------------------------------------------------------
// Depthwise conv (causal fwd / anti-causal reversed-tap bwd) + SiLU, bf16.
// ------------------------------------------------------------------
__global__ void conv_kernel(const bf16* __restrict__ xi_buf, const float* __restrict__ cw,
                            const float* __restrict__ cb, bf16* __restrict__ xc, int reverse) {
    int g = blockIdx.x * blockDim.x + threadIdx.x;
    int c  = g % DINNER;
    int bl = g / DINNER;
    int l = bl % SEQ;
    int b = bl / SEQ;
    float w[4];
#pragma unroll
    for (int k = 0; k < 4; ++k) w[k] = cw[c * 4 + k];
    const bf16* xi = xi_buf + (size_t)b * SEQ * DINNER + c;
    float acc = cb[c];
    if (!reverse) {
#pragma unroll
        for (int k = 0; k < 4; ++k) {
            int ll = l - 3 + k;
            if (ll >= 0) acc += b2f(xi[(size_t)ll * DINNER]) * w[k];
        }
    } else {
#pragma unroll
        for (int j = 0; j < 4; ++j) {
            int ll = l + j;
            if (ll < SEQ) acc += b2f(xi[(size_t)ll * DINNER]) * w[3 - j];
        }
    }
    xc[(size_t)bl * DINNER + c] = f2b(acc / (1.f + __expf(-acc)));
}

// ------------------------------------------------------------------
// dt precompute: dt[row,c] = softplus(dtb[c] + sum_r xp[row,r]*dtwT[r,c]).
// R1 rewrite: weights live in REGISTERS (24 float4 per thread, thread owns
// 4 fixed channels), block iterates DTR_R tokens with xp staged in LDS
// (broadcast reads). Weight L1 traffic drops DTR_R x vs per-token re-read,
// which was the R0 bottleneck (VALUBusy 78%, 61.5 us, HBM 11%).
// ------------------------------------------------------------------
__global__ __launch_bounds__(192) void dt_kernel(const float* __restrict__ xp,
                                                 const float* __restrict__ dtwT,
                                                 const float* __restrict__ dtb,
                                                 float* __restrict__ dtf) {
    __shared__ float xps[DTR_R][DTRANK];
    int tid = threadIdx.x;          // 0..191: c4 group index
    int c4  = tid * 4;
    float4 wv[DTRANK];
#pragma unroll
    for (int r = 0; r < DTRANK; ++r)
        wv[r] = *(const float4*)(dtwT + r * DINNER + c4);
    float4 bias = *(const float4*)(dtb + c4);

    size_t row0 = (size_t)blockIdx.x * DTR_R;
    for (int i = tid; i < DTR_R * DTRANK; i += 192) {
        int s = i / DTRANK, r = i % DTRANK;
        xps[s][r] = xp[(row0 + s) * 56 + r];
    }
    __syncthreads();

#pragma unroll 2
    for (int s = 0; s < DTR_R; ++s) {
        float4 dt = bias;
#pragma unroll
        for (int r = 0; r < DTRANK; ++r) {
            float xv = xps[s][r];
            dt.x += xv * wv[r].x;
            dt.y += xv * wv[r].y;
            dt.z += xv * wv[r].z;
            dt.w += xv * wv[r].w;
        }
        dt.x = fmaxf(dt.x, 0.f) + log1pf(__expf(-fabsf(dt.x)));
        dt.y = fmaxf(dt.y, 0.f) + log1pf(__expf(-fabsf(dt.y)));
        dt.z = fmaxf(dt.z, 0.f) + log1pf(__expf(-fabsf(dt.z)));
        dt.w = fmaxf(dt.w, 0.f) + log1pf(__expf(-fabsf(dt.w)));
        *(float4*)(dtf + (row0 + s) * DINNER + c4) = dt;
    }
}

// ------------------------------------------------------------------
// Chunked selective scan over TC chunks of CL steps.
// PHASE 0: from h=0: P = prod dA, h_end -> states.  (structured: P=Q^(n+1))
// stitch : serial compose; stores h_in into the P slot.
// PHASE 1: from h_in, emit y = C.h + D*xc  (silu(z) applied later by MODE-3).
// Structured A path (flag[1]==0): dA[n] = e1^(n+1), e1 = exp(dt*Av0):
// 1 transcendental per step instead of 16.
// ------------------------------------------------------------------
template <int PHASE>
__global__ void scan_phase(const float* __restrict__ xp, const bf16* __restrict__ xc,
                           const float* __restrict__ dtf, const float* __restrict__ Alog,
                           const float* __restrict__ Dg, float* __restrict__ states,
                           bf16* __restrict__ ydir, int reverse, const int* __restrict__ flag) {
    __shared__ float xps[16][32];
    bool generic = (flag[1] != 0);
    int tid = threadIdx.x;
    int bidx = blockIdx.x;
    int tc  = bidx % TC;
    int cgb = bidx / TC;       // bb*6+cg
    int cg  = cgb % 6;
    int bb  = cgb / 6;
    int c = cg * 128 + tid;

    float Av0 = -__expf(Alog[c * DSTATE]);
    float Av[DSTATE];
    if (generic) {
#pragma unroll
        for (int n = 0; n < DSTATE; ++n) Av[n] = -__expf(Alog[c * DSTATE + n]);
    }
    float Dv = Dg[c];

    float h[DSTATE];
    float Q = 1.f, Pg[DSTATE];
    size_t sbase = (size_t)bidx * 32;
    if (PHASE == 0) {
#pragma unroll
        for (int n = 0; n < DSTATE; ++n) { h[n] = 0.f; Pg[n] = 1.f; }
    } else {
#pragma unroll
        for (int n = 0; n < DSTATE; ++n) h[n] = states[(sbase + n) * 128 + tid];
    }

    const size_t brow = (size_t)bb * SEQ;
    for (int g0 = tc * CL; g0 < tc * CL + CL; g0 += 16) {
        __syncthreads();
        for (int i = tid; i < 16 * 32; i += 128) {
            int s = i >> 5, r = i & 31;
            int t = g0 + s;
            int tr = reverse ? (SEQ - 1 - t) : t;
            xps[s][r] = xp[(brow + tr) * 56 + 24 + r];
        }
        __syncthreads();
        for (int s = 0; s < 16; ++s) {
            int t = g0 + s;
            int tr = reverse ? (SEQ - 1 - t) : t;
            size_t row = brow + tr;
            float dt  = dtf[row * DINNER + c];
            float xcv = b2f(xc[row * DINNER + c]);
            float dtx = dt * xcv;
            float accv = 0.f;
            if (!generic) {
                float e1 = __expf(dt * Av0);
                float d = e1;
#pragma unroll
                for (int n = 0; n < DSTATE; ++n) {
                    h[n] = d * h[n] + dtx * xps[s][n];
                    if (PHASE == 1) accv += h[n] * xps[s][16 + n];
                    d *= e1;
                }
                if (PHASE == 0) Q *= e1;
            } else {
#pragma unroll
                for (int n = 0; n < DSTATE; ++n) {
                    float dA = __expf(dt * Av[n]);
                    h[n] = dA * h[n] + dtx * xps[s][n];
                    if (PHASE == 0) Pg[n] *= dA;
                    else accv += h[n] * xps[s][16 + n];
                }
            }
            if (PHASE == 1)
                ydir[row * DINNER + c] = f2b(accv + xcv * Dv);
        }
    }
    if (PHASE == 0) {
        if (!generic) {
            float d = Q;
#pragma unroll
            for (int n = 0; n < DSTATE; ++n) { Pg[n] = d; d *= Q; }
        }
#pragma unroll
        for (int n = 0; n < DSTATE; ++n) {
            states[(sbase + n) * 128 + tid]      = Pg[n];
            states[(sbase + 16 + n) * 128 + tid] = h[n];
        }
    }
}

__global__ void scan_stitch(float* __restrict__ states) {
    int tid = threadIdx.x;
    int cgb = blockIdx.x;
    float h[DSTATE];
#pragma unroll
    for (int n = 0; n < DSTATE; ++n) h[n] = 0.f;
    for (int tc = 0; tc < TC; ++tc) {
        size_t base = ((size_t)cgb * TC + tc) * 32;
#pragma unroll
        for (int n = 0; n < DSTATE; ++n) {
            float Pv = states[(base + n) * 128 + tid];
            float ev = states[(base + 16 + n) * 128 + tid];
            states[(base + n) * 128 + tid] = h[n];   // h_in for this chunk
            h[n] = Pv * h[n] + ev;
        }
    }
}

// ------------------------------------------------------------------
extern "C" void kernel_launch(void* const* d_in, const int* in_sizes, int n_in,
                              void* d_out, int out_size, void* d_ws, size_t ws_size,
                              hipStream_t stream) {
    (void)n_in; (void)out_size;
    bool dict_order = (in_sizes[4] < 2048);
    int fbase = dict_order ? 5 : 3;
    int bbase = dict_order ? 14 : 12;
    int gwi = dict_order ? 3 : 21;
    int gbi = dict_order ? 4 : 22;

    auto al = [](size_t b) { return (b + 255) & ~(size_t)255; };
    char* ws = (char*)d_ws;
    size_t off = 0;
    auto alloc = [&](size_t bytes) {
        void* p = ws + off;
        off += al(bytes);
        return p;
    };

    int* flag = (int*)alloc(256);

    CvtF pf{};
    int cf = 0;
    auto addf = [&](int idx, int n) {
        float* d = (float*)alloc((size_t)n * 4);
        pf.src[cf] = d_in[idx]; pf.dst[cf] = d; pf.n[cf] = n; ++cf;
        return d;
    };
    float* ln_gc   = addf(1, DMODEL);
    float* ln_bc   = addf(2, DMODEL);
    float* gate_bc = addf(gbi, DMODEL);
    float* convw_f[2], *convb_f[2], *dtw_f[2], *dtb_f[2], *alog_f[2], *dd_f[2];
    for (int d = 0; d < 2; ++d) {
        int base = d ? bbase : fbase;
        convw_f[d] = addf(base + 1, DINNER * 4);
        convb_f[d] = addf(base + 2, DINNER);
        dtw_f[d]   = addf(base + 4, DINNER * DTRANK);
        dtb_f[d]   = addf(base + 5, DINNER);
        alog_f[d]  = addf(base + 6, DINNER * DSTATE);
        dd_f[d]    = addf(base + 7, DINNER);
    }

    CvtB pb{};
    int cb = 0;
    auto addb = [&](int idx, int n, size_t alloc_n) {
        bf16* d = (bf16*)alloc(alloc_n * 2);
        pb.src[cb] = d_in[idx]; pb.dst[cb] = d; pb.n[cb] = n; ++cb;
        return d;
    };
    bf16* gate_wb = addb(gwi, DMODEL * 2 * DMODEL, (size_t)DMODEL * 2 * DMODEL);
    bf16 *inw_b[2], *xpw_b[2], *outw_b[2];
    for (int d = 0; d < 2; ++d) {
        int base = d ? bbase : fbase;
        inw_b[d]  = addb(base + 0, 2 * DINNER * DMODEL, (size_t)2 * DINNER * DMODEL);
        xpw_b[d]  = addb(base + 3, 56 * DINNER, (size_t)128 * DINNER);  // padded
        outw_b[d] = addb(base + 8, DMODEL * DINNER, (size_t)DMODEL * DINNER);
    }

    // transposed dt weights (f32, [24][768]) for coalesced dt_kernel
    float* dtwT_f[2];
    for (int d = 0; d < 2; ++d)
        dtwT_f[d] = (float*)alloc((size_t)DTRANK * DINNER * 4);

    size_t fixed = off;

    // per-chunk activations (zb eliminated; dt f32 added; states at TC=32)
    auto chunk_need = [&](int bc) {
        size_t T = (size_t)bc * SEQ;
        return al(T * DMODEL * 2)                       // xn
             + 2 * al(T * DINNER * 2)                   // xi(/ydir), xc
             + al(T * 56 * 4)                           // xp f32
             + al(T * DINNER * 4)                       // dt f32
             + al(T * DINNER * 2)                       // ycat
             + al((size_t)bc * 6 * TC * 32 * 128 * 4);  // scan states
    };
    int Bc = 32;
    while (Bc > 1 && fixed + chunk_need(Bc) > ws_size) Bc >>= 1;
    size_t T = (size_t)Bc * SEQ;

    bf16*  xn_c   = (bf16*)alloc(T * DMODEL * 2);
    bf16*  xib    = (bf16*)alloc(T * DINNER * 2);
    bf16*  xcb    = (bf16*)alloc(T * DINNER * 2);
    float* xpb    = (float*)alloc(T * 56 * 4);
    float* dtfb   = (float*)alloc(T * DINNER * 4);
    bf16*  ycat   = (bf16*)alloc(T * DINNER * 2);
    float* states = (float*)alloc((size_t)Bc * 6 * TC * 32 * 128 * 4);
    bf16*  ydir   = xib;  // alias: xi dead after conv

    hipMemsetAsync(flag, 0, 8, stream);
    for (int d = 0; d < 2; ++d)
        hipMemsetAsync(xpw_b[d], 0, (size_t)128 * DINNER * 2, stream);
    detect_kernel<<<1, 256, 0, stream>>>((const unsigned short*)d_in[0], flag);
    convert_f_kernel<<<dim3(8, 15), 256, 0, stream>>>(pf, flag);
    convert_b_kernel<<<dim3(32, 7), 256, 0, stream>>>(pb, flag);
    struct_check<<<3, 256, 0, stream>>>(alog_f[0], flag);
    struct_check<<<3, 256, 0, stream>>>(alog_f[1], flag);
    for (int d = 0; d < 2; ++d)
        transpose_dtw<<<(DINNER * DTRANK + 255) / 256, 256, 0, stream>>>(dtw_f[d], dtwT_f[d]);

    for (int c0 = 0; c0 < BATCH; c0 += Bc) {
        size_t tok0 = (size_t)c0 * SEQ;

        ln_kernel<<<(unsigned)(T / 4), 256, 0, stream>>>(
            d_in[0], tok0 * DMODEL, ln_gc, ln_bc, xn_c, flag);

        for (int dir = 0; dir < 2; ++dir) {
            // in-proj xi half
            gemm_mfma<0><<<dim3(DINNER / 128, T / 128), 256, 0, stream>>>(
                xn_c, inw_b[dir], DMODEL, DMODEL, DMODEL,
                xib, DINNER, 0, nullptr, nullptr, nullptr, 0, nullptr, flag);
            conv_kernel<<<(unsigned)((T * DINNER) / 256), 256, 0, stream>>>(
                xib, convw_f[dir], convb_f[dir], xcb, dir);
            // x-proj (56 cols padded to 128)
            gemm_mfma<2><<<dim3(1, T / 128), 256, 0, stream>>>(
                xcb, xpw_b[dir], DINNER, DINNER, DINNER,
                nullptr, 0, 0, xpb, nullptr, nullptr, 0, nullptr, flag);
            dt_kernel<<<(unsigned)(T / DTR_R), 192, 0, stream>>>(
                xpb, dtwT_f[dir], dtb_f[dir], dtfb);
            // chunked scan
            scan_phase<0><<<Bc * 6 * TC, 128, 0, stream>>>(
                xpb, xcb, dtfb, alog_f[dir], dd_f[dir], states, nullptr, dir, flag);
            scan_stitch<<<Bc * 6, 128, 0, stream>>>(states);
            scan_phase<1><<<Bc * 6 * TC, 128, 0, stream>>>(
                xpb, xcb, dtfb, alog_f[dir], dd_f[dir], states, ydir, dir, flag);
            // z in-proj GEMM with fused gating: ydir *= silu(z)
            gemm_mfma<3><<<dim3(DINNER / 128, T / 128), 256, 0, stream>>>(
                xn_c, inw_b[dir] + (size_t)DINNER * DMODEL, DMODEL, DMODEL, DMODEL,
                ydir, DINNER, 0, nullptr, nullptr, nullptr, 0, nullptr, flag);
            // out-proj into ycat columns [dir*384, dir*384+384)
            gemm_mfma<0><<<dim3(DMODEL / 128, T / 128), 256, 0, stream>>>(
                ydir, outw_b[dir], DINNER, DINNER, DINNER,
                ycat, DINNER, dir * DMODEL, nullptr, nullptr, nullptr, 0, nullptr, flag);
        }

        // gate GEMM + combine + residual
        gemm_mfma<1><<<dim3(DMODEL / 128, T / 128), 256, 0, stream>>>(
            ycat, gate_wb, DINNER, DINNER, DINNER,
            nullptr, 0, 0, nullptr, gate_bc, d_in[0], tok0 * DMODEL, d_out, flag);
    }
}

// Round 3
// 1517.898 us; speedup vs baseline: 1.0250x; 1.0250x over previous
//
#include <hip/hip_runtime.h>
#include <hip/hip_bf16.h>

#define BATCH  32
#define SEQ    1024
#define DMODEL 384
#define DINNER 768
#define DSTATE 16
#define DTRANK 24
#define NTOK   (BATCH * SEQ)
#define TC     32             // time chunks for parallel scan
#define CL     (SEQ / TC)     // 32 steps per chunk
#define DTR_R  64             // tokens per dt block

typedef __hip_bfloat16 bf16;
typedef __attribute__((ext_vector_type(8))) short frag_ab;  // 8 bf16
typedef __attribute__((ext_vector_type(4))) float frag_cd;  // 4 f32

__device__ __forceinline__ float b2f(bf16 v) { return __bfloat162float(v); }
__device__ __forceinline__ bf16  f2b(float v) { return __float2bfloat16(v); }
__device__ __forceinline__ float ldx(const void* p, size_t i, bool f32m) {
    return f32m ? ((const float*)p)[i] : b2f(((const bf16*)p)[i]);
}

// ------------------------------------------------------------------
// Input-dtype detection (f32 vs bf16). Verified R5: inputs are f32.
// ------------------------------------------------------------------
__global__ void detect_kernel(const unsigned short* __restrict__ x, int* flag) {
    int bad = 0;
    for (int i = threadIdx.x; i < 16384; i += 256) {
        int e = (x[i] >> 7) & 0xFF;
        bad |= (e >= 0xE0);
    }
    if (bad) atomicOr(flag, 1);
}

// ------------------------------------------------------------------
// A-structure check: Av[n]/Av[0] == n+1 (A_log = log(1..16) broadcast).
// Sets flag[1]=1 if NOT structured -> scan uses generic 16-exp path.
// ------------------------------------------------------------------
__global__ void struct_check(const float* __restrict__ alog, int* flag) {
    int c = blockIdx.x * 256 + threadIdx.x;
    if (c >= DINNER) return;
    float a0 = __expf(alog[c * 16]);
    int bad = 0;
#pragma unroll
    for (int n = 1; n < DSTATE; ++n) {
        float r = __expf(alog[c * 16 + n]) / a0;
        bad |= (fabsf(r - (float)(n + 1)) > 1e-3f * (n + 1));
    }
    if (bad) atomicOr(flag + 1, 1);
}

// ------------------------------------------------------------------
// Weight conversion: small params -> f32, GEMM weights -> bf16.
// ------------------------------------------------------------------
struct CvtF { const void* src[15]; float* dst[15]; int n[15]; };
struct CvtB { const void* src[7];  bf16*  dst[7];  int n[7];  };

__global__ void convert_f_kernel(CvtF p, const int* __restrict__ flag) {
    bool f32m = (*flag != 0);
    int y = blockIdx.y;
    const void* s = p.src[y];
    float* d = p.dst[y];
    int n = p.n[y];
    for (int i = blockIdx.x * 256 + threadIdx.x; i < n; i += gridDim.x * 256)
        d[i] = ldx(s, i, f32m);
}
__global__ void convert_b_kernel(CvtB p, const int* __restrict__ flag) {
    bool f32m = (*flag != 0);
    int y = blockIdx.y;
    const void* s = p.src[y];
    bf16* d = p.dst[y];
    int n = p.n[y];
    for (int i = blockIdx.x * 256 + threadIdx.x; i < n; i += gridDim.x * 256)
        d[i] = f2b(ldx(s, i, f32m));
}

// ------------------------------------------------------------------
// dtw transpose: [768][24] f32 -> [24][768] f32 so dt_kernel loads are
// coalesced (consecutive channels = consecutive addresses).
// ------------------------------------------------------------------
__global__ void transpose_dtw(const float* __restrict__ w, float* __restrict__ wt) {
    int i = blockIdx.x * 256 + threadIdx.x;
    if (i >= DINNER * DTRANK) return;
    int c = i / DTRANK, r = i % DTRANK;
    wt[r * DINNER + c] = w[i];
}

// ------------------------------------------------------------------
// LayerNorm: one wave per row of 384; writes bf16 xn.
// ------------------------------------------------------------------
__global__ void ln_kernel(const void* __restrict__ x, size_t xoff,
                          const float* __restrict__ gamma, const float* __restrict__ beta,
                          bf16* __restrict__ xn, const int* __restrict__ flag) {
    bool f32m = (*flag != 0);
    int wave = threadIdx.x >> 6;
    int lane = threadIdx.x & 63;
    int row  = blockIdx.x * 4 + wave;
    size_t base = xoff + (size_t)row * DMODEL;
    float v[6];
    float s = 0.f, s2 = 0.f;
#pragma unroll
    for (int i = 0; i < 6; ++i) {
        v[i] = ldx(x, base + lane + i * 64, f32m);
        s += v[i];
        s2 += v[i] * v[i];
    }
#pragma unroll
    for (int off = 32; off >= 1; off >>= 1) {
        s  += __shfl_down(s, off, 64);
        s2 += __shfl_down(s2, off, 64);
    }
    s  = __shfl(s, 0, 64);
    s2 = __shfl(s2, 0, 64);
    float mu   = s / DMODEL;
    float var  = s2 / DMODEL - mu * mu;
    float rstd = rsqrtf(var + 1e-5f);
    bf16* xnr = xn + (size_t)row * DMODEL;
#pragma unroll
    for (int i = 0; i < 6; ++i)
        xnr[lane + i * 64] = f2b((v[i] - mu) * rstd * gamma[lane + i * 64] + beta[lane + i * 64]);
}

// ------------------------------------------------------------------
// MFMA bf16 GEMM, 128x128 tile, BK=32, 256 threads (2x2 waves of 64x64).
// C[M,N] = A[M,K] @ W[N,K]^T.
// MODE 0: bf16 store (ldc, cofs).        MODE 1: gate epilogue -> d_out.
// MODE 2: f32 store, 56 valid cols.      MODE 3: z epilogue: C *= silu(v).
// ------------------------------------------------------------------
template <int MODE>
__global__ __launch_bounds__(256) void gemm_mfma(
    const bf16* __restrict__ A, const bf16* __restrict__ W,
    int K, int lda, int ldw,
    bf16* __restrict__ C, int ldc, int cofs,
    float* __restrict__ Cf,
    const float* __restrict__ gb, const void* __restrict__ xg, size_t xoff,
    void* __restrict__ outg, const int* __restrict__ flag) {
    __shared__ bf16 Als[128][32];
    __shared__ bf16 Bls[128][32];
    int tid = threadIdx.x;
    int lane = tid & 63;
    int w = tid >> 6;
    int wm = w & 1, wn = w >> 1;
    int m0 = blockIdx.y * 128, n0 = blockIdx.x * 128;
    int row = tid >> 2, kc = tid & 3;
    int mr = lane & 15, quad = lane >> 4;

    frag_cd acc[4][4] = {};

    for (int k0 = 0; k0 < K; k0 += 32) {
        uint4 a0 = *(const uint4*)(A + (size_t)(m0 + row) * lda + k0 + kc * 8);
        uint4 a1 = *(const uint4*)(A + (size_t)(m0 + 64 + row) * lda + k0 + kc * 8);
        uint4 b0 = *(const uint4*)(W + (size_t)(n0 + row) * ldw + k0 + kc * 8);
        uint4 b1 = *(const uint4*)(W + (size_t)(n0 + 64 + row) * ldw + k0 + kc * 8);
        __syncthreads();
        *(uint4*)&Als[row][kc * 8]      = a0;
        *(uint4*)&Als[64 + row][kc * 8] = a1;
        *(uint4*)&Bls[row][kc * 8]      = b0;
        *(uint4*)&Bls[64 + row][kc * 8] = b1;
        __syncthreads();
        frag_ab af[4], bfr[4];
#pragma unroll
        for (int r = 0; r < 4; ++r)
            af[r] = *(const frag_ab*)&Als[wm * 64 + r * 16 + mr][quad * 8];
#pragma unroll
        for (int c = 0; c < 4; ++c)
            bfr[c] = *(const frag_ab*)&Bls[wn * 64 + c * 16 + mr][quad * 8];
#pragma unroll
        for (int r = 0; r < 4; ++r)
#pragma unroll
            for (int c = 0; c < 4; ++c)
                acc[r][c] = __builtin_amdgcn_mfma_f32_16x16x32_bf16(af[r], bfr[c], acc[r][c], 0, 0, 0);
    }

    bool f32m = (MODE == 1) ? (*flag != 0) : false;
#pragma unroll
    for (int r = 0; r < 4; ++r) {
#pragma unroll
        for (int c = 0; c < 4; ++c) {
#pragma unroll
            for (int reg = 0; reg < 4; ++reg) {
                int gm = m0 + wm * 64 + r * 16 + quad * 4 + reg;
                int gn = n0 + wn * 64 + c * 16 + mr;
                float v = acc[r][c][reg];
                if (MODE == 0) {
                    C[(size_t)gm * ldc + cofs + gn] = f2b(v);
                } else if (MODE == 2) {
                    if (gn < DTRANK + 2 * DSTATE) Cf[(size_t)gm * 56 + gn] = v;
                } else if (MODE == 3) {  // ydir *= silu(z),  v == z
                    size_t idx = (size_t)gm * ldc + cofs + gn;
                    float y = b2f(C[idx]);
                    float sz = v / (1.f + __expf(-v));
                    C[idx] = f2b(y * sz);
                } else {  // gate: g*yf + (1-g)*yb + x  (A == ycat)
                    float g   = 1.f / (1.f + __expf(-(v + gb[gn])));
                    float yfv = b2f(A[(size_t)gm * DINNER + gn]);
                    float ybv = b2f(A[(size_t)gm * DINNER + DMODEL + gn]);
                    size_t gi = xoff + (size_t)gm * DMODEL + gn;
                    float xv  = f32m ? ((const float*)xg)[gi] : b2f(((const bf16*)xg)[gi]);
                    float rr  = g * yfv + (1.f - g) * ybv + xv;
                    if (f32m) ((float*)outg)[gi] = rr;
                    else      ((bf16*)outg)[gi]  = f2b(rr);
                }
            }
        }
    }
}

// ------------------------------------------------------------------
// Depthwise conv (causal fwd / anti-causal reversed-tap bwd) + SiLU, bf16.
// ------------------------------------------------------------------
__global__ void conv_kernel(const bf16* __restrict__ xi_buf, const float* __restrict__ cw,
                            const float* __restrict__ cb, bf16* __restrict__ xc, int reverse) {
    int g = blockIdx.x * blockDim.x + threadIdx.x;
    int c  = g % DINNER;
    int bl = g / DINNER;
    int l = bl % SEQ;
    int b = bl / SEQ;
    float w[4];
#pragma unroll
    for (int k = 0; k < 4; ++k) w[k] = cw[c * 4 + k];
    const bf16* xi = xi_buf + (size_t)b * SEQ * DINNER + c;
    float acc = cb[c];
    if (!reverse) {
#pragma unroll
        for (int k = 0; k < 4; ++k) {
            int ll = l - 3 + k;
            if (ll >= 0) acc += b2f(xi[(size_t)ll * DINNER]) * w[k];
        }
    } else {
#pragma unroll
        for (int j = 0; j < 4; ++j) {
            int ll = l + j;
            if (ll < SEQ) acc += b2f(xi[(size_t)ll * DINNER]) * w[3 - j];
        }
    }
    xc[(size_t)bl * DINNER + c] = f2b(acc / (1.f + __expf(-acc)));
}

// ------------------------------------------------------------------
// dt precompute: dt[row,c] = softplus(dtb[c] + sum_r xp[row,r]*dtwT[r,c]).
// R2 rewrite: ONE channel per thread -> 24 scalar f32 weights (24 VGPRs,
// statically indexed; R1's 24xfloat4=96 VGPRs made the compiler re-load
// from L1 every token, VGPR_Count=84 proved it). Block = 256 threads =
// 256 consecutive channels (coalesced weight load + coalesced store);
// 64 tokens staged in LDS, read via broadcast ds_read_b128.
// ------------------------------------------------------------------
__global__ __launch_bounds__(256) void dt_kernel(const float* __restrict__ xp,
                                                 const float* __restrict__ dtwT,
                                                 const float* __restrict__ dtb,
                                                 float* __restrict__ dtf) {
    __shared__ float4 xps[DTR_R][6];   // 24 xp values per token
    int tid = threadIdx.x;
    int c = blockIdx.y * 256 + tid;
    float w[DTRANK];
#pragma unroll
    for (int r = 0; r < DTRANK; ++r) w[r] = dtwT[r * DINNER + c];
    float bias = dtb[c];

    size_t row0 = (size_t)blockIdx.x * DTR_R;
    for (int i = tid; i < DTR_R * 6; i += 256) {
        int s = i / 6, q = i % 6;
        xps[s][q] = *(const float4*)(xp + (row0 + s) * 56 + q * 4);
    }
    __syncthreads();

    for (int s = 0; s < DTR_R; ++s) {
        float acc = bias;
#pragma unroll
        for (int q = 0; q < 6; ++q) {
            float4 xv = xps[s][q];
            acc += xv.x * w[q * 4 + 0];
            acc += xv.y * w[q * 4 + 1];
            acc += xv.z * w[q * 4 + 2];
            acc += xv.w * w[q * 4 + 3];
        }
        acc = fmaxf(acc, 0.f) + log1pf(__expf(-fabsf(acc)));  // softplus
        dtf[(row0 + s) * DINNER + c] = acc;
    }
}

// ------------------------------------------------------------------
// Chunked selective scan over TC chunks of CL steps.
// PHASE 0: from h=0: P = prod dA, h_end -> states.  (structured: P=Q^(n+1))
// stitch : serial compose; stores h_in into the P slot.
// PHASE 1: from h_in, emit y = C.h + D*xc  (silu(z) applied later by MODE-3).
// Structured A path (flag[1]==0): dA[n] = e1^(n+1), e1 = exp(dt*Av0):
// 1 transcendental per step instead of 16.
// ------------------------------------------------------------------
template <int PHASE>
__global__ void scan_phase(const float* __restrict__ xp, const bf16* __restrict__ xc,
                           const float* __restrict__ dtf, const float* __restrict__ Alog,
                           const float* __restrict__ Dg, float* __restrict__ states,
                           bf16* __restrict__ ydir, int reverse, const int* __restrict__ flag) {
    __shared__ float xps[16][32];
    bool generic = (flag[1] != 0);
    int tid = threadIdx.x;
    int bidx = blockIdx.x;
    int tc  = bidx % TC;
    int cgb = bidx / TC;       // bb*6+cg
    int cg  = cgb % 6;
    int bb  = cgb / 6;
    int c = cg * 128 + tid;

    float Av0 = -__expf(Alog[c * DSTATE]);
    float Av[DSTATE];
    if (generic) {
#pragma unroll
        for (int n = 0; n < DSTATE; ++n) Av[n] = -__expf(Alog[c * DSTATE + n]);
    }
    float Dv = Dg[c];

    float h[DSTATE];
    float Q = 1.f, Pg[DSTATE];
    size_t sbase = (size_t)bidx * 32;
    if (PHASE == 0) {
#pragma unroll
        for (int n = 0; n < DSTATE; ++n) { h[n] = 0.f; Pg[n] = 1.f; }
    } else {
#pragma unroll
        for (int n = 0; n < DSTATE; ++n) h[n] = states[(sbase + n) * 128 + tid];
    }

    const size_t brow = (size_t)bb * SEQ;
    for (int g0 = tc * CL; g0 < tc * CL + CL; g0 += 16) {
        __syncthreads();
        for (int i = tid; i < 16 * 32; i += 128) {
            int s = i >> 5, r = i & 31;
            int t = g0 + s;
            int tr = reverse ? (SEQ - 1 - t) : t;
            xps[s][r] = xp[(brow + tr) * 56 + 24 + r];
        }
        __syncthreads();
        for (int s = 0; s < 16; ++s) {
            int t = g0 + s;
            int tr = reverse ? (SEQ - 1 - t) : t;
            size_t row = brow + tr;
            float dt  = dtf[row * DINNER + c];
            float xcv = b2f(xc[row * DINNER + c]);
            float dtx = dt * xcv;
            float accv = 0.f;
            if (!generic) {
                float e1 = __expf(dt * Av0);
                float d = e1;
#pragma unroll
                for (int n = 0; n < DSTATE; ++n) {
                    h[n] = d * h[n] + dtx * xps[s][n];
                    if (PHASE == 1) accv += h[n] * xps[s][16 + n];
                    d *= e1;
                }
                if (PHASE == 0) Q *= e1;
            } else {
#pragma unroll
                for (int n = 0; n < DSTATE; ++n) {
                    float dA = __expf(dt * Av[n]);
                    h[n] = dA * h[n] + dtx * xps[s][n];
                    if (PHASE == 0) Pg[n] *= dA;
                    else accv += h[n] * xps[s][16 + n];
                }
            }
            if (PHASE == 1)
                ydir[row * DINNER + c] = f2b(accv + xcv * Dv);
        }
    }
    if (PHASE == 0) {
        if (!generic) {
            float d = Q;
#pragma unroll
            for (int n = 0; n < DSTATE; ++n) { Pg[n] = d; d *= Q; }
        }
#pragma unroll
        for (int n = 0; n < DSTATE; ++n) {
            states[(sbase + n) * 128 + tid]      = Pg[n];
            states[(sbase + 16 + n) * 128 + tid] = h[n];
        }
    }
}

__global__ void scan_stitch(float* __restrict__ states) {
    int tid = threadIdx.x;
    int cgb = blockIdx.x;
    float h[DSTATE];
#pragma unroll
    for (int n = 0; n < DSTATE; ++n) h[n] = 0.f;
    for (int tc = 0; tc < TC; ++tc) {
        size_t base = ((size_t)cgb * TC + tc) * 32;
#pragma unroll
        for (int n = 0; n < DSTATE; ++n) {
            float Pv = states[(base + n) * 128 + tid];
            float ev = states[(base + 16 + n) * 128 + tid];
            states[(base + n) * 128 + tid] = h[n];   // h_in for this chunk
            h[n] = Pv * h[n] + ev;
        }
    }
}

// ------------------------------------------------------------------
extern "C" void kernel_launch(void* const* d_in, const int* in_sizes, int n_in,
                              void* d_out, int out_size, void* d_ws, size_t ws_size,
                              hipStream_t stream) {
    (void)n_in; (void)out_size;
    bool dict_order = (in_sizes[4] < 2048);
    int fbase = dict_order ? 5 : 3;
    int bbase = dict_order ? 14 : 12;
    int gwi = dict_order ? 3 : 21;
    int gbi = dict_order ? 4 : 22;

    auto al = [](size_t b) { return (b + 255) & ~(size_t)255; };
    char* ws = (char*)d_ws;
    size_t off = 0;
    auto alloc = [&](size_t bytes) {
        void* p = ws + off;
        off += al(bytes);
        return p;
    };

    int* flag = (int*)alloc(256);

    CvtF pf{};
    int cf = 0;
    auto addf = [&](int idx, int n) {
        float* d = (float*)alloc((size_t)n * 4);
        pf.src[cf] = d_in[idx]; pf.dst[cf] = d; pf.n[cf] = n; ++cf;
        return d;
    };
    float* ln_gc   = addf(1, DMODEL);
    float* ln_bc   = addf(2, DMODEL);
    float* gate_bc = addf(gbi, DMODEL);
    float* convw_f[2], *convb_f[2], *dtw_f[2], *dtb_f[2], *alog_f[2], *dd_f[2];
    for (int d = 0; d < 2; ++d) {
        int base = d ? bbase : fbase;
        convw_f[d] = addf(base + 1, DINNER * 4);
        convb_f[d] = addf(base + 2, DINNER);
        dtw_f[d]   = addf(base + 4, DINNER * DTRANK);
        dtb_f[d]   = addf(base + 5, DINNER);
        alog_f[d]  = addf(base + 6, DINNER * DSTATE);
        dd_f[d]    = addf(base + 7, DINNER);
    }

    CvtB pb{};
    int cb = 0;
    auto addb = [&](int idx, int n, size_t alloc_n) {
        bf16* d = (bf16*)alloc(alloc_n * 2);
        pb.src[cb] = d_in[idx]; pb.dst[cb] = d; pb.n[cb] = n; ++cb;
        return d;
    };
    bf16* gate_wb = addb(gwi, DMODEL * 2 * DMODEL, (size_t)DMODEL * 2 * DMODEL);
    bf16 *inw_b[2], *xpw_b[2], *outw_b[2];
    for (int d = 0; d < 2; ++d) {
        int base = d ? bbase : fbase;
        inw_b[d]  = addb(base + 0, 2 * DINNER * DMODEL, (size_t)2 * DINNER * DMODEL);
        xpw_b[d]  = addb(base + 3, 56 * DINNER, (size_t)128 * DINNER);  // padded
        outw_b[d] = addb(base + 8, DMODEL * DINNER, (size_t)DMODEL * DINNER);
    }

    // transposed dt weights (f32, [24][768]) for coalesced dt_kernel
    float* dtwT_f[2];
    for (int d = 0; d < 2; ++d)
        dtwT_f[d] = (float*)alloc((size_t)DTRANK * DINNER * 4);

    size_t fixed = off;

    // per-chunk activations (zb eliminated; dt f32 added; states at TC=32)
    auto chunk_need = [&](int bc) {
        size_t T = (size_t)bc * SEQ;
        return al(T * DMODEL * 2)                       // xn
             + 2 * al(T * DINNER * 2)                   // xi(/ydir), xc
             + al(T * 56 * 4)                           // xp f32
             + al(T * DINNER * 4)                       // dt f32
             + al(T * DINNER * 2)                       // ycat
             + al((size_t)bc * 6 * TC * 32 * 128 * 4);  // scan states
    };
    int Bc = 32;
    while (Bc > 1 && fixed + chunk_need(Bc) > ws_size) Bc >>= 1;
    size_t T = (size_t)Bc * SEQ;

    bf16*  xn_c   = (bf16*)alloc(T * DMODEL * 2);
    bf16*  xib    = (bf16*)alloc(T * DINNER * 2);
    bf16*  xcb    = (bf16*)alloc(T * DINNER * 2);
    float* xpb    = (float*)alloc(T * 56 * 4);
    float* dtfb   = (float*)alloc(T * DINNER * 4);
    bf16*  ycat   = (bf16*)alloc(T * DINNER * 2);
    float* states = (float*)alloc((size_t)Bc * 6 * TC * 32 * 128 * 4);
    bf16*  ydir   = xib;  // alias: xi dead after conv

    hipMemsetAsync(flag, 0, 8, stream);
    for (int d = 0; d < 2; ++d)
        hipMemsetAsync(xpw_b[d], 0, (size_t)128 * DINNER * 2, stream);
    detect_kernel<<<1, 256, 0, stream>>>((const unsigned short*)d_in[0], flag);
    convert_f_kernel<<<dim3(8, 15), 256, 0, stream>>>(pf, flag);
    convert_b_kernel<<<dim3(32, 7), 256, 0, stream>>>(pb, flag);
    struct_check<<<3, 256, 0, stream>>>(alog_f[0], flag);
    struct_check<<<3, 256, 0, stream>>>(alog_f[1], flag);
    for (int d = 0; d < 2; ++d)
        transpose_dtw<<<(DINNER * DTRANK + 255) / 256, 256, 0, stream>>>(dtw_f[d], dtwT_f[d]);

    for (int c0 = 0; c0 < BATCH; c0 += Bc) {
        size_t tok0 = (size_t)c0 * SEQ;

        ln_kernel<<<(unsigned)(T / 4), 256, 0, stream>>>(
            d_in[0], tok0 * DMODEL, ln_gc, ln_bc, xn_c, flag);

        for (int dir = 0; dir < 2; ++dir) {
            // in-proj xi half
            gemm_mfma<0><<<dim3(DINNER / 128, T / 128), 256, 0, stream>>>(
                xn_c, inw_b[dir], DMODEL, DMODEL, DMODEL,
                xib, DINNER, 0, nullptr, nullptr, nullptr, 0, nullptr, flag);
            conv_kernel<<<(unsigned)((T * DINNER) / 256), 256, 0, stream>>>(
                xib, convw_f[dir], convb_f[dir], xcb, dir);
            // x-proj (56 cols padded to 128)
            gemm_mfma<2><<<dim3(1, T / 128), 256, 0, stream>>>(
                xcb, xpw_b[dir], DINNER, DINNER, DINNER,
                nullptr, 0, 0, xpb, nullptr, nullptr, 0, nullptr, flag);
            dt_kernel<<<dim3((unsigned)(T / DTR_R), 3), 256, 0, stream>>>(
                xpb, dtwT_f[dir], dtb_f[dir], dtfb);
            // chunked scan
            scan_phase<0><<<Bc * 6 * TC, 128, 0, stream>>>(
                xpb, xcb, dtfb, alog_f[dir], dd_f[dir], states, nullptr, dir, flag);
            scan_stitch<<<Bc * 6, 128, 0, stream>>>(states);
            scan_phase<1><<<Bc * 6 * TC, 128, 0, stream>>>(
                xpb, xcb, dtfb, alog_f[dir], dd_f[dir], states, ydir, dir, flag);
            // z in-proj GEMM with fused gating: ydir *= silu(z)
            gemm_mfma<3><<<dim3(DINNER / 128, T / 128), 256, 0, stream>>>(
                xn_c, inw_b[dir] + (size_t)DINNER * DMODEL, DMODEL, DMODEL, DMODEL,
                ydir, DINNER, 0, nullptr, nullptr, nullptr, 0, nullptr, flag);
            // out-proj into ycat columns [dir*384, dir*384+384)
            gemm_mfma<0><<<dim3(DMODEL / 128, T / 128), 256, 0, stream>>>(
                ydir, outw_b[dir], DINNER, DINNER, DINNER,
                ycat, DINNER, dir * DMODEL, nullptr, nullptr, nullptr, 0, nullptr, flag);
        }

        // gate GEMM + combine + residual
        gemm_mfma<1><<<dim3(DMODEL / 128, T / 128), 256, 0, stream>>>(
            ycat, gate_wb, DINNER, DINNER, DINNER,
            nullptr, 0, 0, nullptr, gate_bc, d_in[0], tok0 * DMODEL, d_out, flag);
    }
}

// Round 5
// 1370.565 us; speedup vs baseline: 1.1352x; 1.1075x over previous
//
#include <hip/hip_runtime.h>
#include <hip/hip_bf16.h>

#define BATCH  32
#define SEQ    1024
#define DMODEL 384
#define DINNER 768
#define DSTATE 16
#define DTRANK 24
#define NTOK   (BATCH * SEQ)
#define TC     32             // time chunks for parallel scan
#define CL     (SEQ / TC)     // 32 steps per chunk
#define DTR_R  32             // tokens per dt block

typedef __hip_bfloat16 bf16;
typedef __attribute__((ext_vector_type(8))) short frag_ab;  // 8 bf16
typedef __attribute__((ext_vector_type(4))) float frag_cd;  // 4 f32

__device__ __forceinline__ float b2f(bf16 v) { return __bfloat162float(v); }
__device__ __forceinline__ bf16  f2b(float v) { return __float2bfloat16(v); }
__device__ __forceinline__ float ldx(const void* p, size_t i, bool f32m) {
    return f32m ? ((const float*)p)[i] : b2f(((const bf16*)p)[i]);
}

// ------------------------------------------------------------------
// Input-dtype detection (f32 vs bf16). Verified R5: inputs are f32.
// ------------------------------------------------------------------
__global__ void detect_kernel(const unsigned short* __restrict__ x, int* flag) {
    int bad = 0;
    for (int i = threadIdx.x; i < 16384; i += 256) {
        int e = (x[i] >> 7) & 0xFF;
        bad |= (e >= 0xE0);
    }
    if (bad) atomicOr(flag, 1);
}

// ------------------------------------------------------------------
// A-structure check: Av[n]/Av[0] == n+1 (A_log = log(1..16) broadcast).
// Sets flag[1]=1 if NOT structured -> scan uses generic 16-exp path.
// ------------------------------------------------------------------
__global__ void struct_check(const float* __restrict__ alog, int* flag) {
    int c = blockIdx.x * 256 + threadIdx.x;
    if (c >= DINNER) return;
    float a0 = __expf(alog[c * 16]);
    int bad = 0;
#pragma unroll
    for (int n = 1; n < DSTATE; ++n) {
        float r = __expf(alog[c * 16 + n]) / a0;
        bad |= (fabsf(r - (float)(n + 1)) > 1e-3f * (n + 1));
    }
    if (bad) atomicOr(flag + 1, 1);
}

// ------------------------------------------------------------------
// Weight conversion: small params -> f32, GEMM weights -> bf16.
// ------------------------------------------------------------------
struct CvtF { const void* src[15]; float* dst[15]; int n[15]; };
struct CvtB { const void* src[7];  bf16*  dst[7];  int n[7];  };

__global__ void convert_f_kernel(CvtF p, const int* __restrict__ flag) {
    bool f32m = (*flag != 0);
    int y = blockIdx.y;
    const void* s = p.src[y];
    float* d = p.dst[y];
    int n = p.n[y];
    for (int i = blockIdx.x * 256 + threadIdx.x; i < n; i += gridDim.x * 256)
        d[i] = ldx(s, i, f32m);
}
__global__ void convert_b_kernel(CvtB p, const int* __restrict__ flag) {
    bool f32m = (*flag != 0);
    int y = blockIdx.y;
    const void* s = p.src[y];
    bf16* d = p.dst[y];
    int n = p.n[y];
    for (int i = blockIdx.x * 256 + threadIdx.x; i < n; i += gridDim.x * 256)
        d[i] = f2b(ldx(s, i, f32m));
}

// ------------------------------------------------------------------
// dtw transpose: [768][24] f32 -> [24][768] f32 so dt_kernel loads are
// coalesced (consecutive channels = consecutive addresses).
// ------------------------------------------------------------------
__global__ void transpose_dtw(const float* __restrict__ w, float* __restrict__ wt) {
    int i = blockIdx.x * 256 + threadIdx.x;
    if (i >= DINNER * DTRANK) return;
    int c = i / DTRANK, r = i % DTRANK;
    wt[r * DINNER + c] = w[i];
}

// ------------------------------------------------------------------
// LayerNorm: one wave per row of 384; writes bf16 xn.
// ------------------------------------------------------------------
__global__ void ln_kernel(const void* __restrict__ x, size_t xoff,
                          const float* __restrict__ gamma, const float* __restrict__ beta,
                          bf16* __restrict__ xn, const int* __restrict__ flag) {
    bool f32m = (*flag != 0);
    int wave = threadIdx.x >> 6;
    int lane = threadIdx.x & 63;
    int row  = blockIdx.x * 4 + wave;
    size_t base = xoff + (size_t)row * DMODEL;
    float v[6];
    float s = 0.f, s2 = 0.f;
#pragma unroll
    for (int i = 0; i < 6; ++i) {
        v[i] = ldx(x, base + lane + i * 64, f32m);
        s += v[i];
        s2 += v[i] * v[i];
    }
#pragma unroll
    for (int off = 32; off >= 1; off >>= 1) {
        s  += __shfl_down(s, off, 64);
        s2 += __shfl_down(s2, off, 64);
    }
    s  = __shfl(s, 0, 64);
    s2 = __shfl(s2, 0, 64);
    float mu   = s / DMODEL;
    float var  = s2 / DMODEL - mu * mu;
    float rstd = rsqrtf(var + 1e-5f);
    bf16* xnr = xn + (size_t)row * DMODEL;
#pragma unroll
    for (int i = 0; i < 6; ++i)
        xnr[lane + i * 64] = f2b((v[i] - mu) * rstd * gamma[lane + i * 64] + beta[lane + i * 64]);
}

// ------------------------------------------------------------------
// MFMA bf16 GEMM, 128x128 tile, BK=32, 256 threads (2x2 waves of 64x64).
// C[M,N] = A[M,K] @ W[N,K]^T.
// MODE 0: bf16 store (ldc, cofs).        MODE 1: gate epilogue -> d_out.
// MODE 2: f32 store, 56 valid cols.      MODE 3: z epilogue: C *= silu(v).
// ------------------------------------------------------------------
template <int MODE>
__global__ __launch_bounds__(256) void gemm_mfma(
    const bf16* __restrict__ A, const bf16* __restrict__ W,
    int K, int lda, int ldw,
    bf16* __restrict__ C, int ldc, int cofs,
    float* __restrict__ Cf,
    const float* __restrict__ gb, const void* __restrict__ xg, size_t xoff,
    void* __restrict__ outg, const int* __restrict__ flag) {
    __shared__ bf16 Als[128][32];
    __shared__ bf16 Bls[128][32];
    int tid = threadIdx.x;
    int lane = tid & 63;
    int w = tid >> 6;
    int wm = w & 1, wn = w >> 1;
    int m0 = blockIdx.y * 128, n0 = blockIdx.x * 128;
    int row = tid >> 2, kc = tid & 3;
    int mr = lane & 15, quad = lane >> 4;

    frag_cd acc[4][4] = {};

    for (int k0 = 0; k0 < K; k0 += 32) {
        uint4 a0 = *(const uint4*)(A + (size_t)(m0 + row) * lda + k0 + kc * 8);
        uint4 a1 = *(const uint4*)(A + (size_t)(m0 + 64 + row) * lda + k0 + kc * 8);
        uint4 b0 = *(const uint4*)(W + (size_t)(n0 + row) * ldw + k0 + kc * 8);
        uint4 b1 = *(const uint4*)(W + (size_t)(n0 + 64 + row) * ldw + k0 + kc * 8);
        __syncthreads();
        *(uint4*)&Als[row][kc * 8]      = a0;
        *(uint4*)&Als[64 + row][kc * 8] = a1;
        *(uint4*)&Bls[row][kc * 8]      = b0;
        *(uint4*)&Bls[64 + row][kc * 8] = b1;
        __syncthreads();
        frag_ab af[4], bfr[4];
#pragma unroll
        for (int r = 0; r < 4; ++r)
            af[r] = *(const frag_ab*)&Als[wm * 64 + r * 16 + mr][quad * 8];
#pragma unroll
        for (int c = 0; c < 4; ++c)
            bfr[c] = *(const frag_ab*)&Bls[wn * 64 + c * 16 + mr][quad * 8];
#pragma unroll
        for (int r = 0; r < 4; ++r)
#pragma unroll
            for (int c = 0; c < 4; ++c)
                acc[r][c] = __builtin_amdgcn_mfma_f32_16x16x32_bf16(af[r], bfr[c], acc[r][c], 0, 0, 0);
    }

    bool f32m = (MODE == 1) ? (*flag != 0) : false;
#pragma unroll
    for (int r = 0; r < 4; ++r) {
#pragma unroll
        for (int c = 0; c < 4; ++c) {
#pragma unroll
            for (int reg = 0; reg < 4; ++reg) {
                int gm = m0 + wm * 64 + r * 16 + quad * 4 + reg;
                int gn = n0 + wn * 64 + c * 16 + mr;
                float v = acc[r][c][reg];
                if (MODE == 0) {
                    C[(size_t)gm * ldc + cofs + gn] = f2b(v);
                } else if (MODE == 2) {
                    if (gn < DTRANK + 2 * DSTATE) Cf[(size_t)gm * 56 + gn] = v;
                } else if (MODE == 3) {  // ydir *= silu(z),  v == z
                    size_t idx = (size_t)gm * ldc + cofs + gn;
                    float y = b2f(C[idx]);
                    float sz = v / (1.f + __expf(-v));
                    C[idx] = f2b(y * sz);
                } else {  // gate: g*yf + (1-g)*yb + x  (A == ycat)
                    float g   = 1.f / (1.f + __expf(-(v + gb[gn])));
                    float yfv = b2f(A[(size_t)gm * DINNER + gn]);
                    float ybv = b2f(A[(size_t)gm * DINNER + DMODEL + gn]);
                    size_t gi = xoff + (size_t)gm * DMODEL + gn;
                    float xv  = f32m ? ((const float*)xg)[gi] : b2f(((const bf16*)xg)[gi]);
                    float rr  = g * yfv + (1.f - g) * ybv + xv;
                    if (f32m) ((float*)outg)[gi] = rr;
                    else      ((bf16*)outg)[gi]  = f2b(rr);
                }
            }
        }
    }
}

// ------------------------------------------------------------------
// Depthwise conv (causal fwd / anti-causal reversed-tap bwd) + SiLU, bf16.
// ------------------------------------------------------------------
__global__ void conv_kernel(const bf16* __restrict__ xi_buf, const float* __restrict__ cw,
                            const float* __restrict__ cb, bf16* __restrict__ xc, int reverse) {
    int g = blockIdx.x * blockDim.x + threadIdx.x;
    int c  = g % DINNER;
    int bl = g / DINNER;
    int l = bl % SEQ;
    int b = bl / SEQ;
    float w[4];
#pragma unroll
    for (int k = 0; k < 4; ++k) w[k] = cw[c * 4 + k];
    const bf16* xi = xi_buf + (size_t)b * SEQ * DINNER + c;
    float acc = cb[c];
    if (!reverse) {
#pragma unroll
        for (int k = 0; k < 4; ++k) {
            int ll = l - 3 + k;
            if (ll >= 0) acc += b2f(xi[(size_t)ll * DINNER]) * w[k];
        }
    } else {
#pragma unroll
        for (int j = 0; j < 4; ++j) {
            int ll = l + j;
            if (ll < SEQ) acc += b2f(xi[(size_t)ll * DINNER]) * w[3 - j];
        }
    }
    xc[(size_t)bl * DINNER + c] = f2b(acc / (1.f + __expf(-acc)));
}

// ------------------------------------------------------------------
// dt precompute: dt[row,c] = softplus(dtb[c] + sum_r xp[row,r]*dtwT[r,c]).
// R3/R4: (a) 24 scalar weights PINNED in VGPRs via empty inline-asm "+v"
// (R1/R2 showed the compiler sinks/rematerializes the loads otherwise).
// (b) hardware softplus via amdgcn builtins (v_exp_f32 = 2^x,
// v_log_f32 = log2 x): max(x,0)+ln2*log2(1+2^(-|x|*log2e)) -- ~7 HW ops
// vs log1pf's libm path. (c) 2-token unroll. (d) DTR_R=32 -> 1536 blocks.
// ------------------------------------------------------------------
__global__ __launch_bounds__(256, 4) void dt_kernel(const float* __restrict__ xp,
                                                    const float* __restrict__ dtwT,
                                                    const float* __restrict__ dtb,
                                                    float* __restrict__ dtf) {
    __shared__ float4 xps[DTR_R][6];   // 24 xp values per token
    int tid = threadIdx.x;
    int c = blockIdx.y * 256 + tid;
    float w[DTRANK];
#pragma unroll
    for (int r = 0; r < DTRANK; ++r) w[r] = dtwT[r * DINNER + c];
#pragma unroll
    for (int r = 0; r < DTRANK; ++r) asm volatile("" : "+v"(w[r]));  // pin in VGPRs
    float bias = dtb[c];

    size_t row0 = (size_t)blockIdx.x * DTR_R;
    for (int i = tid; i < DTR_R * 6; i += 256) {
        int s = i / 6, q = i % 6;
        xps[s][q] = *(const float4*)(xp + (row0 + s) * 56 + q * 4);
    }
    __syncthreads();

    for (int s = 0; s < DTR_R; s += 2) {
        float a0 = bias, a1 = bias;
#pragma unroll
        for (int q = 0; q < 6; ++q) {
            float4 x0 = xps[s][q];
            float4 x1 = xps[s + 1][q];
            a0 += x0.x * w[q * 4 + 0];  a1 += x1.x * w[q * 4 + 0];
            a0 += x0.y * w[q * 4 + 1];  a1 += x1.y * w[q * 4 + 1];
            a0 += x0.z * w[q * 4 + 2];  a1 += x1.z * w[q * 4 + 2];
            a0 += x0.w * w[q * 4 + 3];  a1 += x1.w * w[q * 4 + 3];
        }
        // hardware softplus: max(x,0) + ln2*log2(1 + 2^(-|x|*log2e))
        float e0 = __builtin_amdgcn_exp2f(fabsf(a0) * -1.44269504f);
        float e1 = __builtin_amdgcn_exp2f(fabsf(a1) * -1.44269504f);
        a0 = fmaxf(a0, 0.f) + 0.69314718f * __builtin_amdgcn_logf(1.f + e0);
        a1 = fmaxf(a1, 0.f) + 0.69314718f * __builtin_amdgcn_logf(1.f + e1);
        dtf[(row0 + s) * DINNER + c]     = a0;
        dtf[(row0 + s + 1) * DINNER + c] = a1;
    }
}

// ------------------------------------------------------------------
// Chunked selective scan over TC chunks of CL steps.
// PHASE 0: from h=0: P = prod dA, h_end -> states.  (structured: P=Q^(n+1))
// stitch : serial compose; stores h_in into the P slot.
// PHASE 1: from h_in, emit y = C.h + D*xc  (silu(z) applied later by MODE-3).
// Structured A path (flag[1]==0): dA[n] = e1^(n+1), e1 = exp(dt*Av0):
// 1 transcendental per step instead of 16.
// ------------------------------------------------------------------
template <int PHASE>
__global__ void scan_phase(const float* __restrict__ xp, const bf16* __restrict__ xc,
                           const float* __restrict__ dtf, const float* __restrict__ Alog,
                           const float* __restrict__ Dg, float* __restrict__ states,
                           bf16* __restrict__ ydir, int reverse, const int* __restrict__ flag) {
    __shared__ float xps[16][32];
    bool generic = (flag[1] != 0);
    int tid = threadIdx.x;
    int bidx = blockIdx.x;
    int tc  = bidx % TC;
    int cgb = bidx / TC;       // bb*6+cg
    int cg  = cgb % 6;
    int bb  = cgb / 6;
    int c = cg * 128 + tid;

    float Av0 = -__expf(Alog[c * DSTATE]);
    float Av[DSTATE];
    if (generic) {
#pragma unroll
        for (int n = 0; n < DSTATE; ++n) Av[n] = -__expf(Alog[c * DSTATE + n]);
    }
    float Dv = Dg[c];

    float h[DSTATE];
    float Q = 1.f, Pg[DSTATE];
    size_t sbase = (size_t)bidx * 32;
    if (PHASE == 0) {
#pragma unroll
        for (int n = 0; n < DSTATE; ++n) { h[n] = 0.f; Pg[n] = 1.f; }
    } else {
#pragma unroll
        for (int n = 0; n < DSTATE; ++n) h[n] = states[(sbase + n) * 128 + tid];
    }

    const size_t brow = (size_t)bb * SEQ;
    for (int g0 = tc * CL; g0 < tc * CL + CL; g0 += 16) {
        __syncthreads();
        for (int i = tid; i < 16 * 32; i += 128) {
            int s = i >> 5, r = i & 31;
            int t = g0 + s;
            int tr = reverse ? (SEQ - 1 - t) : t;
            xps[s][r] = xp[(brow + tr) * 56 + 24 + r];
        }
        __syncthreads();
        for (int s = 0; s < 16; ++s) {
            int t = g0 + s;
            int tr = reverse ? (SEQ - 1 - t) : t;
            size_t row = brow + tr;
            float dt  = dtf[row * DINNER + c];
            float xcv = b2f(xc[row * DINNER + c]);
            float dtx = dt * xcv;
            float accv = 0.f;
            if (!generic) {
                float e1 = __expf(dt * Av0);
                float d = e1;
#pragma unroll
                for (int n = 0; n < DSTATE; ++n) {
                    h[n] = d * h[n] + dtx * xps[s][n];
                    if (PHASE == 1) accv += h[n] * xps[s][16 + n];
                    d *= e1;
                }
                if (PHASE == 0) Q *= e1;
            } else {
#pragma unroll
                for (int n = 0; n < DSTATE; ++n) {
                    float dA = __expf(dt * Av[n]);
                    h[n] = dA * h[n] + dtx * xps[s][n];
                    if (PHASE == 0) Pg[n] *= dA;
                    else accv += h[n] * xps[s][16 + n];
                }
            }
            if (PHASE == 1)
                ydir[row * DINNER + c] = f2b(accv + xcv * Dv);
        }
    }
    if (PHASE == 0) {
        if (!generic) {
            float d = Q;
#pragma unroll
            for (int n = 0; n < DSTATE; ++n) { Pg[n] = d; d *= Q; }
        }
#pragma unroll
        for (int n = 0; n < DSTATE; ++n) {
            states[(sbase + n) * 128 + tid]      = Pg[n];
            states[(sbase + 16 + n) * 128 + tid] = h[n];
        }
    }
}

__global__ void scan_stitch(float* __restrict__ states) {
    int tid = threadIdx.x;
    int cgb = blockIdx.x;
    float h[DSTATE];
#pragma unroll
    for (int n = 0; n < DSTATE; ++n) h[n] = 0.f;
    for (int tc = 0; tc < TC; ++tc) {
        size_t base = ((size_t)cgb * TC + tc) * 32;
#pragma unroll
        for (int n = 0; n < DSTATE; ++n) {
            float Pv = states[(base + n) * 128 + tid];
            float ev = states[(base + 16 + n) * 128 + tid];
            states[(base + n) * 128 + tid] = h[n];   // h_in for this chunk
            h[n] = Pv * h[n] + ev;
        }
    }
}

// ------------------------------------------------------------------
extern "C" void kernel_launch(void* const* d_in, const int* in_sizes, int n_in,
                              void* d_out, int out_size, void* d_ws, size_t ws_size,
                              hipStream_t stream) {
    (void)n_in; (void)out_size;
    bool dict_order = (in_sizes[4] < 2048);
    int fbase = dict_order ? 5 : 3;
    int bbase = dict_order ? 14 : 12;
    int gwi = dict_order ? 3 : 21;
    int gbi = dict_order ? 4 : 22;

    auto al = [](size_t b) { return (b + 255) & ~(size_t)255; };
    char* ws = (char*)d_ws;
    size_t off = 0;
    auto alloc = [&](size_t bytes) {
        void* p = ws + off;
        off += al(bytes);
        return p;
    };

    int* flag = (int*)alloc(256);

    CvtF pf{};
    int cf = 0;
    auto addf = [&](int idx, int n) {
        float* d = (float*)alloc((size_t)n * 4);
        pf.src[cf] = d_in[idx]; pf.dst[cf] = d; pf.n[cf] = n; ++cf;
        return d;
    };
    float* ln_gc   = addf(1, DMODEL);
    float* ln_bc   = addf(2, DMODEL);
    float* gate_bc = addf(gbi, DMODEL);
    float* convw_f[2], *convb_f[2], *dtw_f[2], *dtb_f[2], *alog_f[2], *dd_f[2];
    for (int d = 0; d < 2; ++d) {
        int base = d ? bbase : fbase;
        convw_f[d] = addf(base + 1, DINNER * 4);
        convb_f[d] = addf(base + 2, DINNER);
        dtw_f[d]   = addf(base + 4, DINNER * DTRANK);
        dtb_f[d]   = addf(base + 5, DINNER);
        alog_f[d]  = addf(base + 6, DINNER * DSTATE);
        dd_f[d]    = addf(base + 7, DINNER);
    }

    CvtB pb{};
    int cb = 0;
    auto addb = [&](int idx, int n, size_t alloc_n) {
        bf16* d = (bf16*)alloc(alloc_n * 2);
        pb.src[cb] = d_in[idx]; pb.dst[cb] = d; pb.n[cb] = n; ++cb;
        return d;
    };
    bf16* gate_wb = addb(gwi, DMODEL * 2 * DMODEL, (size_t)DMODEL * 2 * DMODEL);
    bf16 *inw_b[2], *xpw_b[2], *outw_b[2];
    for (int d = 0; d < 2; ++d) {
        int base = d ? bbase : fbase;
        inw_b[d]  = addb(base + 0, 2 * DINNER * DMODEL, (size_t)2 * DINNER * DMODEL);
        xpw_b[d]  = addb(base + 3, 56 * DINNER, (size_t)128 * DINNER);  // padded
        outw_b[d] = addb(base + 8, DMODEL * DINNER, (size_t)DMODEL * DINNER);
    }

    // transposed dt weights (f32, [24][768]) for coalesced dt_kernel
    float* dtwT_f[2];
    for (int d = 0; d < 2; ++d)
        dtwT_f[d] = (float*)alloc((size_t)DTRANK * DINNER * 4);

    size_t fixed = off;

    // per-chunk activations (zb eliminated; dt f32 added; states at TC=32)
    auto chunk_need = [&](int bc) {
        size_t T = (size_t)bc * SEQ;
        return al(T * DMODEL * 2)                       // xn
             + 2 * al(T * DINNER * 2)                   // xi(/ydir), xc
             + al(T * 56 * 4)                           // xp f32
             + al(T * DINNER * 4)                       // dt f32
             + al(T * DINNER * 2)                       // ycat
             + al((size_t)bc * 6 * TC * 32 * 128 * 4);  // scan states
    };
    int Bc = 32;
    while (Bc > 1 && fixed + chunk_need(Bc) > ws_size) Bc >>= 1;
    size_t T = (size_t)Bc * SEQ;

    bf16*  xn_c   = (bf16*)alloc(T * DMODEL * 2);
    bf16*  xib    = (bf16*)alloc(T * DINNER * 2);
    bf16*  xcb    = (bf16*)alloc(T * DINNER * 2);
    float* xpb    = (float*)alloc(T * 56 * 4);
    float* dtfb   = (float*)alloc(T * DINNER * 4);
    bf16*  ycat   = (bf16*)alloc(T * DINNER * 2);
    float* states = (float*)alloc((size_t)Bc * 6 * TC * 32 * 128 * 4);
    bf16*  ydir   = xib;  // alias: xi dead after conv

    hipMemsetAsync(flag, 0, 8, stream);
    for (int d = 0; d < 2; ++d)
        hipMemsetAsync(xpw_b[d], 0, (size_t)128 * DINNER * 2, stream);
    detect_kernel<<<1, 256, 0, stream>>>((const unsigned short*)d_in[0], flag);
    convert_f_kernel<<<dim3(8, 15), 256, 0, stream>>>(pf, flag);
    convert_b_kernel<<<dim3(32, 7), 256, 0, stream>>>(pb, flag);
    struct_check<<<3, 256, 0, stream>>>(alog_f[0], flag);
    struct_check<<<3, 256, 0, stream>>>(alog_f[1], flag);
    for (int d = 0; d < 2; ++d)
        transpose_dtw<<<(DINNER * DTRANK + 255) / 256, 256, 0, stream>>>(dtw_f[d], dtwT_f[d]);

    for (int c0 = 0; c0 < BATCH; c0 += Bc) {
        size_t tok0 = (size_t)c0 * SEQ;

        ln_kernel<<<(unsigned)(T / 4), 256, 0, stream>>>(
            d_in[0], tok0 * DMODEL, ln_gc, ln_bc, xn_c, flag);

        for (int dir = 0; dir < 2; ++dir) {
            // in-proj xi half
            gemm_mfma<0><<<dim3(DINNER / 128, T / 128), 256, 0, stream>>>(
                xn_c, inw_b[dir], DMODEL, DMODEL, DMODEL,
                xib, DINNER, 0, nullptr, nullptr, nullptr, 0, nullptr, flag);
            conv_kernel<<<(unsigned)((T * DINNER) / 256), 256, 0, stream>>>(
                xib, convw_f[dir], convb_f[dir], xcb, dir);
            // x-proj (56 cols padded to 128)
            gemm_mfma<2><<<dim3(1, T / 128), 256, 0, stream>>>(
                xcb, xpw_b[dir], DINNER, DINNER, DINNER,
                nullptr, 0, 0, xpb, nullptr, nullptr, 0, nullptr, flag);
            dt_kernel<<<dim3((unsigned)(T / DTR_R), 3), 256, 0, stream>>>(
                xpb, dtwT_f[dir], dtb_f[dir], dtfb);
            // chunked scan
            scan_phase<0><<<Bc * 6 * TC, 128, 0, stream>>>(
                xpb, xcb, dtfb, alog_f[dir], dd_f[dir], states, nullptr, dir, flag);
            scan_stitch<<<Bc * 6, 128, 0, stream>>>(states);
            scan_phase<1><<<Bc * 6 * TC, 128, 0, stream>>>(
                xpb, xcb, dtfb, alog_f[dir], dd_f[dir], states, ydir, dir, flag);
            // z in-proj GEMM with fused gating: ydir *= silu(z)
            gemm_mfma<3><<<dim3(DINNER / 128, T / 128), 256, 0, stream>>>(
                xn_c, inw_b[dir] + (size_t)DINNER * DMODEL, DMODEL, DMODEL, DMODEL,
                ydir, DINNER, 0, nullptr, nullptr, nullptr, 0, nullptr, flag);
            // out-proj into ycat columns [dir*384, dir*384+384)
            gemm_mfma<0><<<dim3(DMODEL / 128, T / 128), 256, 0, stream>>>(
                ydir, outw_b[dir], DINNER, DINNER, DINNER,
                ycat, DINNER, dir * DMODEL, nullptr, nullptr, nullptr, 0, nullptr, flag);
        }

        // gate GEMM + combine + residual
        gemm_mfma<1><<<dim3(DMODEL / 128, T / 128), 256, 0, stream>>>(
            ycat, gate_wb, DINNER, DINNER, DINNER,
            nullptr, 0, 0, nullptr, gate_bc, d_in[0], tok0 * DMODEL, d_out, flag);
    }
}